// Round 1
// 1082.380 us; speedup vs baseline: 1.0172x; 1.0172x over previous
//
#include <hip/hip_runtime.h>
#include <hip/hip_bf16.h>
#include <stdint.h>

#define IGNORE_INDEX (-100)

constexpr int M_ = 8192;    // B*S tokens
constexpr int K_ = 2048;    // D
constexpr int N_ = 32000;   // V

constexpr int BM = 128, BN = 128;

typedef __attribute__((ext_vector_type(4)))  float f32x4;
typedef __attribute__((ext_vector_type(16))) float f32x16;
typedef __attribute__((ext_vector_type(4)))  int   i32x4;
typedef __attribute__((ext_vector_type(8)))  int   i32x8;
typedef __attribute__((ext_vector_type(4)))  unsigned int u32x4;
typedef __attribute__((ext_vector_type(8)))  __bf16 bf16x8;

// quantization scales (powers of 2, exactly undone in fp32 epilogue)
#define SCALE_A 8.0f
#define SCALE_W 1024.0f
#define INV_S   (1.0f / (8.0f * 1024.0f))

// ---------- fp32 -> bf16 packing (fallback path) ----------
__device__ __forceinline__ unsigned pack_bf16(float f0, float f1) {
    unsigned u0 = __builtin_bit_cast(unsigned, f0) + 0x8000u;
    unsigned u1 = __builtin_bit_cast(unsigned, f1) + 0x8000u;
    return __builtin_amdgcn_perm(u1, u0, 0x07060302u);
}
__device__ __forceinline__ u32x4 pack8(f32x4 lo, f32x4 hi) {
    u32x4 r;
    r[0] = pack_bf16(lo[0], lo[1]);
    r[1] = pack_bf16(lo[2], lo[3]);
    r[2] = pack_bf16(hi[0], hi[1]);
    r[3] = pack_bf16(hi[2], hi[3]);
    return r;
}

// ---------- async global->LDS, 16B per lane ----------
__device__ __forceinline__ void gll16(const void* g, void* l) {
    __builtin_amdgcn_global_load_lds(
        (const __attribute__((address_space(1))) unsigned int*)g,
        (__attribute__((address_space(3))) unsigned int*)l, 16, 0, 0);
}

__global__ void init_acc(float* p, int n) {
    int i = blockIdx.x * 256 + threadIdx.x;
    if (i < n) p[i] = 0.0f;
}

// n8 groups of 8 fp32 -> 8 fp8 e4m3 (scaled)
__global__ __launch_bounds__(256) void convert_fp8(
    const float* __restrict__ in, unsigned int* __restrict__ out,
    float scale, int n8)
{
    int i = blockIdx.x * 256 + threadIdx.x;
    if (i < n8) {
        f32x4 lo = ((const f32x4*)in)[2 * i];
        f32x4 hi = ((const f32x4*)in)[2 * i + 1];
        int w0 = 0, w1 = 0;
        w0 = __builtin_amdgcn_cvt_pk_fp8_f32(lo[0] * scale, lo[1] * scale, w0, false);
        w0 = __builtin_amdgcn_cvt_pk_fp8_f32(lo[2] * scale, lo[3] * scale, w0, true);
        w1 = __builtin_amdgcn_cvt_pk_fp8_f32(hi[0] * scale, hi[1] * scale, w1, false);
        w1 = __builtin_amdgcn_cvt_pk_fp8_f32(hi[2] * scale, hi[3] * scale, w1, true);
        out[2 * i]     = (unsigned int)w0;
        out[2 * i + 1] = (unsigned int)w1;
    }
}

// -------------- MX-fp8 GEMM, 256 threads, wave tile 64x64 --------------------
// Round-5 redesign. Two structural changes vs round 4:
//  (1) wave tile 32x64 -> 64x64 (2x2 MFMA register reuse): LDS read bytes
//      per MFMA drop 3KB -> 2KB; staging writes 1KB -> 1KB; total LDS
//      demand/MFMA 4KB -> 3KB, lifting the LDS-BW ceiling on MfmaUtil
//      from ~47% to ~63%.
//  (2) double-buffered LDS, one barrier per K-step, DMA issued BEFORE
//      compute of the other buffer (minimum-2-phase pipeline). The old
//      structure drained vmcnt(0) immediately after issuing the loads.
// Layouts unchanged (numerics-verified): A/B frag = 32 contiguous K-bytes,
// rows lane&31, K-half lane>>5; XOR swizzle phys 16B-group = logical ^
// ((row>>1)&3) on both pre-swizzled global source and frag read.
// C/D: col=lane&31, row=(reg&3)+8(reg>>2)+4h.
// acc = 4 x f32x16 = 64 AGPR; ~130 unified regs -> 3 waves/SIMD, 3 blk/CU.

#define MFMA_SC(a, b, c) \
    __builtin_amdgcn_mfma_scale_f32_32x32x64_f8f6f4( \
        (a), (b), (c), 0, 0, 0, 0x7F7F7F7F, 0, 0x7F7F7F7F)

#define STAGE(asb, bsb, koff)                          \
    do {                                               \
        gll16(gA0 + (koff), (asb) + stoff);            \
        gll16(gA1 + (koff), (asb) + stoff + 4096);     \
        gll16(gB0 + (koff), (bsb) + stoff);            \
        gll16(gB1 + (koff), (bsb) + stoff + 4096);     \
    } while (0)

#define COMPUTE(asb, bsb)                                                     \
    do {                                                                      \
        const unsigned char* pA_ = (asb);                                     \
        const unsigned char* pB_ = (bsb);                                     \
        i32x4 aL0 = *(const i32x4*)(pA_ + aoffL);                             \
        i32x4 aH0 = *(const i32x4*)(pA_ + aoffH);                             \
        i32x4 aL1 = *(const i32x4*)(pA_ + aoffL + 2048);                      \
        i32x4 aH1 = *(const i32x4*)(pA_ + aoffH + 2048);                      \
        i32x4 bL0 = *(const i32x4*)(pB_ + boffL);                             \
        i32x4 bH0 = *(const i32x4*)(pB_ + boffH);                             \
        i32x4 bL1 = *(const i32x4*)(pB_ + boffL + 2048);                      \
        i32x4 bH1 = *(const i32x4*)(pB_ + boffH + 2048);                      \
        i32x8 af0 = (i32x8){aL0[0], aL0[1], aL0[2], aL0[3],                   \
                            aH0[0], aH0[1], aH0[2], aH0[3]};                  \
        i32x8 af1 = (i32x8){aL1[0], aL1[1], aL1[2], aL1[3],                   \
                            aH1[0], aH1[1], aH1[2], aH1[3]};                  \
        i32x8 bf0 = (i32x8){bL0[0], bL0[1], bL0[2], bL0[3],                   \
                            bH0[0], bH0[1], bH0[2], bH0[3]};                  \
        i32x8 bf1 = (i32x8){bL1[0], bL1[1], bL1[2], bL1[3],                   \
                            bH1[0], bH1[1], bH1[2], bH1[3]};                  \
        __builtin_amdgcn_s_setprio(1);                                        \
        acc00 = MFMA_SC(af0, bf0, acc00);                                     \
        acc01 = MFMA_SC(af0, bf1, acc01);                                     \
        acc10 = MFMA_SC(af1, bf0, acc10);                                     \
        acc11 = MFMA_SC(af1, bf1, acc11);                                     \
        __builtin_amdgcn_s_setprio(0);                                        \
    } while (0)

__global__ __launch_bounds__(256, 3) void gemm_fp8(
    const unsigned char* __restrict__ A,
    const unsigned char* __restrict__ Wq,
    const int*   __restrict__ tgt,
    float* __restrict__ sumexp,
    float* __restrict__ tgtlogit)
{
    __shared__ __align__(16) unsigned char As[2][BM * 64];
    __shared__ __align__(16) unsigned char Bs[2][BN * 64];
    __shared__ int tg[BM];

    const int tid = threadIdx.x;   // 0..255
    const int mt  = blockIdx.x;    // 0..63 fastest -> adjacent blocks share W tile
    const int nt  = blockIdx.y;    // 0..249

    if (tid < BM) tg[tid] = tgt[mt * BM + tid];

    const int wave = tid >> 6;     // 0..3
    const int lane = tid & 63;
    const int wm   = wave >> 1;    // m wave tile (0..1) -> rows wm*64..+63
    const int wn   = wave & 1;     // n wave tile (0..1) -> cols wn*64..+63

    // --- staging: 4 x gll16/thread covers both 128x64B tiles per K-step ---
    const int srow = tid >> 2;                          // 0..63
    const int spg  = (tid & 3) ^ ((srow >> 1) & 3);     // pre-swizzled 16B grp
    // note: row+64 has the same ((row>>1)&3) swizzle (64>>1 = 32 ≡ 0 mod 4)
    const unsigned char* gA0 = A  + (size_t)(mt * BM + srow) * K_ + spg * 16;
    const unsigned char* gB0 = Wq + (size_t)(nt * BN + srow) * K_ + spg * 16;
    const unsigned char* gA1 = gA0 + (size_t)64 * K_;
    const unsigned char* gB1 = gB0 + (size_t)64 * K_;
    const int stoff = wave * 1024;      // DMA dest: wave-uniform base + 16*lane

    // --- frag read offsets (byte offsets into As/Bs buffer) ---
    const int l31 = lane & 31;
    const int h   = lane >> 5;          // K-half (32B each)
    const int ra  = wm * 64 + l31;      // A frag0 rows; frag1 = +32 (+2048B)
    const int rb  = wn * 64 + l31;      // B frag0 rows; frag1 = +32 (+2048B)
    const int xa  = (ra >> 1) & 3;      // (+32 rows keeps the same swizzle)
    const int xb  = (rb >> 1) & 3;
    const int aoffL = ra * 64 + ((2 * h)     ^ xa) * 16;
    const int aoffH = ra * 64 + ((2 * h + 1) ^ xa) * 16;
    const int boffL = rb * 64 + ((2 * h)     ^ xb) * 16;
    const int boffH = rb * 64 + ((2 * h + 1) ^ xb) * 16;

    f32x16 acc00, acc01, acc10, acc11;
#pragma unroll
    for (int r = 0; r < 16; r++) {
        acc00[r] = 0.f; acc01[r] = 0.f; acc10[r] = 0.f; acc11[r] = 0.f;
    }

    STAGE(As[0], Bs[0], 0);
    __syncthreads();   // drain prologue DMA + tg write

#pragma unroll 1
    for (int kt = 0; kt < K_; kt += 128) {
        // phase A: prefetch kt+64 into buf1 while computing buf0 (tile kt)
        STAGE(As[1], Bs[1], kt + 64);
        __builtin_amdgcn_sched_barrier(0);   // keep DMA issue ahead of ds_reads
        COMPUTE(As[0], Bs[0]);
        __syncthreads();   // all reads of buf0 done + buf1 DMA drained

        // phase B: prefetch kt+128 into buf0 while computing buf1 (kt+64)
        if (kt + 128 < K_) STAGE(As[0], Bs[0], kt + 128);
        __builtin_amdgcn_sched_barrier(0);
        COMPUTE(As[1], Bs[1]);
        __syncthreads();
    }

    // --- epilogue: C/D col=lane&31, row=(reg&3)+8*(reg>>2)+4h ---
    const int c0 = nt * BN + wn * 64 + l31;
#pragma unroll
    for (int reg = 0; reg < 16; reg++) {
        const int rbase = (reg & 3) + 8 * (reg >> 2) + 4 * h;
        {   // m-subtile 0: rows wm*64 + 0..31
            const int lrow = wm * 64 + rbase;
            const int grow = mt * BM + lrow;
            const int t    = tg[lrow];
            float v0 = acc00[reg] * INV_S;
            float v1 = acc01[reg] * INV_S;
            if (t == c0)      tgtlogit[grow] = v0;   // cols wn*64 + 0..31
            if (t == c0 + 32) tgtlogit[grow] = v1;   // cols wn*64 + 32..63
            float rs = __expf(v0) + __expf(v1);
            rs += __shfl_xor(rs, 1);
            rs += __shfl_xor(rs, 2);
            rs += __shfl_xor(rs, 4);
            rs += __shfl_xor(rs, 8);
            rs += __shfl_xor(rs, 16);
            if (l31 == 0) atomicAdd(&sumexp[grow], rs);
        }
        {   // m-subtile 1: rows wm*64 + 32..63
            const int lrow = wm * 64 + 32 + rbase;
            const int grow = mt * BM + lrow;
            const int t    = tg[lrow];
            float v0 = acc10[reg] * INV_S;
            float v1 = acc11[reg] * INV_S;
            if (t == c0)      tgtlogit[grow] = v0;
            if (t == c0 + 32) tgtlogit[grow] = v1;
            float rs = __expf(v0) + __expf(v1);
            rs += __shfl_xor(rs, 1);
            rs += __shfl_xor(rs, 2);
            rs += __shfl_xor(rs, 4);
            rs += __shfl_xor(rs, 8);
            rs += __shfl_xor(rs, 16);
            if (l31 == 0) atomicAdd(&sumexp[grow], rs);
        }
    }
}

// ------------- fallback (round-1 kernel) if ws_size too small ----------------
constexpr int BKf = 32;
constexpr int LDA = BKf + 8;
__global__ __launch_bounds__(256) void gemm_fused_f32(
    const float* __restrict__ A,
    const float* __restrict__ W,
    const int*   __restrict__ tgt,
    float* __restrict__ sumexp,
    float* __restrict__ tgtlogit)
{
    __shared__ __bf16 As[BM * LDA];
    __shared__ __bf16 Bs[BN * LDA];
    __shared__ int    tg[BM];

    const int tid = threadIdx.x;
    const int mt  = blockIdx.x;
    const int nt  = blockIdx.y;
    if (tid < BM) tg[tid] = tgt[mt * BM + tid];

    const int wave = tid >> 6, lane = tid & 63;
    const int wm = wave >> 1, wn = wave & 1;
    const int lquad = lane >> 4, lcol = lane & 15;
    const int srow = tid >> 2, scol = (tid & 3) * 8;

    const float* gA = A + (size_t)(mt * BM + srow) * K_ + scol;
    const float* gB = W + (size_t)(nt * BN + srow) * K_ + scol;
    const size_t rowstep = (size_t)64 * K_;

    f32x4 acc[4][4];
#pragma unroll
    for (int i = 0; i < 4; i++)
#pragma unroll
        for (int j = 0; j < 4; j++) acc[i][j] = (f32x4){0.f, 0.f, 0.f, 0.f};

    for (int kt = 0; kt < K_; kt += BKf) {
        f32x4 a0 = *(const f32x4*)(gA + kt);
        f32x4 a1 = *(const f32x4*)(gA + kt + 4);
        f32x4 a2 = *(const f32x4*)(gA + kt + rowstep);
        f32x4 a3 = *(const f32x4*)(gA + kt + rowstep + 4);
        f32x4 b0 = *(const f32x4*)(gB + kt);
        f32x4 b1 = *(const f32x4*)(gB + kt + 4);
        f32x4 b2 = *(const f32x4*)(gB + kt + rowstep);
        f32x4 b3 = *(const f32x4*)(gB + kt + rowstep + 4);
        __syncthreads();
        *(u32x4*)&As[srow * LDA + scol]        = pack8(a0, a1);
        *(u32x4*)&As[(srow + 64) * LDA + scol] = pack8(a2, a3);
        *(u32x4*)&Bs[srow * LDA + scol]        = pack8(b0, b1);
        *(u32x4*)&Bs[(srow + 64) * LDA + scol] = pack8(b2, b3);
        __syncthreads();
        bf16x8 af[4], bf[4];
#pragma unroll
        for (int f = 0; f < 4; f++) {
            af[f] = *(const bf16x8*)&As[(wm * 64 + f * 16 + lcol) * LDA + lquad * 8];
            bf[f] = *(const bf16x8*)&Bs[(wn * 64 + f * 16 + lcol) * LDA + lquad * 8];
        }
#pragma unroll
        for (int mf = 0; mf < 4; mf++)
#pragma unroll
            for (int nf = 0; nf < 4; nf++)
                acc[mf][nf] = __builtin_amdgcn_mfma_f32_16x16x32_bf16(af[mf], bf[nf], acc[mf][nf], 0, 0, 0);
    }
    const int colbase = nt * BN + wn * 64;
#pragma unroll
    for (int mf = 0; mf < 4; mf++) {
#pragma unroll
        for (int r = 0; r < 4; r++) {
            const int lrow = wm * 64 + mf * 16 + lquad * 4 + r;
            const int grow = mt * BM + lrow;
            const int t    = tg[lrow];
            float rs = 0.f;
#pragma unroll
            for (int nf = 0; nf < 4; nf++) {
                float v = acc[mf][nf][r];
                rs += __expf(v);
                if (t == colbase + nf * 16 + lcol) tgtlogit[grow] = v;
            }
            rs += __shfl_xor(rs, 1);
            rs += __shfl_xor(rs, 2);
            rs += __shfl_xor(rs, 4);
            rs += __shfl_xor(rs, 8);
            if (lcol == 0) atomicAdd(&sumexp[grow], rs);
        }
    }
}

__global__ __launch_bounds__(256) void finalize(
    const float* __restrict__ sumexp,
    const float* __restrict__ tgtlogit,
    const int*   __restrict__ tgt,
    float* __restrict__ out)
{
    float s = 0.f;
    int   c = 0;
    for (int i = threadIdx.x; i < M_; i += 256) {
        int t = tgt[i];
        if (t != IGNORE_INDEX) {
            s += __logf(sumexp[i]) - tgtlogit[i];
            c++;
        }
    }
#pragma unroll
    for (int o = 32; o; o >>= 1) {
        s += __shfl_down(s, o);
        c += __shfl_down(c, o);
    }
    __shared__ float ss[4];
    __shared__ int   cc[4];
    int w = threadIdx.x >> 6;
    if ((threadIdx.x & 63) == 0) { ss[w] = s; cc[w] = c; }
    __syncthreads();
    if (threadIdx.x == 0) {
        float st = ss[0] + ss[1] + ss[2] + ss[3];
        int   ct = cc[0] + cc[1] + cc[2] + cc[3];
        out[0] = st / (float)ct;
    }
}

extern "C" void kernel_launch(void* const* d_in, const int* in_sizes, int n_in,
                              void* d_out, int out_size, void* d_ws, size_t ws_size,
                              hipStream_t stream) {
    const float* hidden  = (const float*)d_in[0];
    const int*   targets = (const int*)d_in[1];
    const float* W       = (const float*)d_in[2];

    float* sumexp   = (float*)d_ws;          // [M_] f32
    float* tgtlogit = sumexp + M_;           // [M_] f32
    float* out      = (float*)d_out;

    unsigned char* Aq = (unsigned char*)d_ws + 2 * M_ * sizeof(float);
    unsigned char* Wq = Aq + (size_t)M_ * K_;
    const size_t need = 2 * M_ * sizeof(float) + (size_t)M_ * K_ + (size_t)N_ * K_;

    init_acc<<<(2 * M_ + 255) / 256, 256, 0, stream>>>(sumexp, 2 * M_);

    if (ws_size >= need) {
        const int a8 = M_ * K_ / 8;          // 2,097,152
        const int w8 = N_ * K_ / 8;          // 8,192,000
        convert_fp8<<<(a8 + 255) / 256, 256, 0, stream>>>(hidden, (unsigned int*)Aq, SCALE_A, a8);
        convert_fp8<<<(w8 + 255) / 256, 256, 0, stream>>>(W, (unsigned int*)Wq, SCALE_W, w8);
        gemm_fp8<<<dim3(M_ / BM, N_ / BN), 256, 0, stream>>>(Aq, Wq, targets, sumexp, tgtlogit);
    } else {
        gemm_fused_f32<<<dim3(M_ / BM, N_ / BN), 256, 0, stream>>>(hidden, W, targets, sumexp, tgtlogit);
    }

    finalize<<<1, 256, 0, stream>>>(sumexp, tgtlogit, targets, out);
}